// Round 15
// baseline (51.787 us; speedup 1.0000x reference)
//
#include <hip/hip_runtime.h>
#include <math.h>

// Problem constants (fixed by reference setup_inputs)
constexpr int B   = 128;
constexpr int T   = 300;
constexpr int D   = 1024;   // video dim
constexpr int DA  = 128;    // audio dim
constexpr int TS  = T - 1;  // 299 similarities per batch
constexpr int K   = 32;
constexpr int KP1 = K + 1;

constexpr int SEGW = 19;    // sims per wave: 16 waves * 19 = 304 >= 299

#define EPS_D 1e-5

__device__ __forceinline__ void loadrow(const float* __restrict__ row, int lane, float r[16]) {
    const float4* f = (const float4*)row;
#pragma unroll
    for (int j = 0; j < 4; ++j) {
        float4 x = f[lane + 64 * j];
        r[4 * j + 0] = x.x; r[4 * j + 1] = x.y;
        r[4 * j + 2] = x.z; r[4 * j + 3] = x.w;
    }
}

// dt = <p,c>, cn = <c,c>, each as two 8-deep f64 chains (same order as
// R12/R13 — bit-identical numerics).
__device__ __forceinline__ void dot_norm(const float p[16], const float c[16],
                                         double& dt, double& cn) {
    double d0 = 0.0, d1 = 0.0, n0 = 0.0, n1 = 0.0;
#pragma unroll
    for (int j = 0; j < 8; ++j) {
        d0 += (double)p[j] * (double)c[j];
        n0 += (double)c[j] * (double)c[j];
    }
#pragma unroll
    for (int j = 8; j < 16; ++j) {
        d1 += (double)p[j] * (double)c[j];
        n1 += (double)c[j] * (double)c[j];
    }
    dt = d0 + d1; cn = n0 + n1;
}

// One block per batch, 1024 threads, ONE dispatch total.
// __launch_bounds__(1024, 4): 16-wave block, 4 waves/EU == exactly 1
// block/CU -> 128-VGPR budget. R13's identical body at the default
// (2 blocks/CU, 64 VGPR) spilled ~5 MB to scratch (WRITE 24.1 vs 18.9 MB).
// Phase A: 16 waves x 19 sims, QUAD iterations — 4 sims per round, rows
//   staged 2-at-a-time (~110 VGPR live, fits in 128), 8 f64 butterflies
//   batched into one 6-step pipeline. absmax 0.0 in 8 prior runs.
// Phase B: LDS rank-select; k=0 gather (t always 0) overlapped before it.
// Phase C: gather remaining 32 video+audio rows (L2/L3-warm).
__global__ __launch_bounds__(1024, 4) void fused3_kernel(const float* __restrict__ video,
                                                         const float* __restrict__ audio,
                                                         float* __restrict__ out) {
    __shared__ float S[TS];
    __shared__ int   idxs[KP1];

    int b    = blockIdx.x;
    int tid  = threadIdx.x;
    int w    = tid >> 6;
    int lane = tid & 63;

    const float* vb = video + (size_t)b * T * D;

    // ---- Phase A ----
    {
        int s0 = w * SEGW;
        float P[16];
        loadrow(vb + (size_t)min(s0, TS) * D, lane, P);

        double pn0 = 0.0, pn1 = 0.0;
#pragma unroll
        for (int j = 0; j < 8; ++j)  pn0 += (double)P[j] * (double)P[j];
#pragma unroll
        for (int j = 8; j < 16; ++j) pn1 += (double)P[j] * (double)P[j];
        double pn = pn0 + pn1;
#pragma unroll
        for (int o = 32; o; o >>= 1) pn += __shfl_xor(pn, o);
        double nprev = sqrt(pn) + EPS_D;

        // 4 quad iterations (16 sims): rows staged 2-at-a-time.
#pragma unroll
        for (int i = 0; i < 16; i += 4) {
            int s = s0 + i;
            double dt1, cn1, dt2, cn2, dt3, cn3, dt4, cn4;
            {
                float cB[16], cC[16];
                loadrow(vb + (size_t)min(s + 1, TS) * D, lane, cB);
                loadrow(vb + (size_t)min(s + 2, TS) * D, lane, cC);
                dot_norm(P,  cB, dt1, cn1);
                dot_norm(cB, cC, dt2, cn2);
#pragma unroll
                for (int j = 0; j < 16; ++j) P[j] = cC[j];
            }
            {
                float cD[16], cE[16];
                loadrow(vb + (size_t)min(s + 3, TS) * D, lane, cD);
                loadrow(vb + (size_t)min(s + 4, TS) * D, lane, cE);
                dot_norm(P,  cD, dt3, cn3);
                dot_norm(cD, cE, dt4, cn4);
#pragma unroll
                for (int j = 0; j < 16; ++j) P[j] = cE[j];
            }
            // one batched butterfly: 8 independent f64 chains
#pragma unroll
            for (int o = 32; o; o >>= 1) {
                dt1 += __shfl_xor(dt1, o); cn1 += __shfl_xor(cn1, o);
                dt2 += __shfl_xor(dt2, o); cn2 += __shfl_xor(cn2, o);
                dt3 += __shfl_xor(dt3, o); cn3 += __shfl_xor(cn3, o);
                dt4 += __shfl_xor(dt4, o); cn4 += __shfl_xor(cn4, o);
            }
            double n1 = sqrt(cn1) + EPS_D, n2 = sqrt(cn2) + EPS_D;
            double n3 = sqrt(cn3) + EPS_D, n4 = sqrt(cn4) + EPS_D;
            if (lane == 0) {
                if (s < TS)     S[s]     = (float)(fabs(dt1) / (nprev * n1));
                if (s + 1 < TS) S[s + 1] = (float)(fabs(dt2) / (n1 * n2));
                if (s + 2 < TS) S[s + 2] = (float)(fabs(dt3) / (n2 * n3));
                if (s + 3 < TS) S[s + 3] = (float)(fabs(dt4) / (n3 * n4));
            }
            nprev = n4;
        }
        // pair tail (i = 16,17)
        {
            int s = s0 + 16;
            float cB[16], cC[16];
            loadrow(vb + (size_t)min(s + 1, TS) * D, lane, cB);
            loadrow(vb + (size_t)min(s + 2, TS) * D, lane, cC);
            double dt1, cn1, dt2, cn2;
            dot_norm(P,  cB, dt1, cn1);
            dot_norm(cB, cC, dt2, cn2);
#pragma unroll
            for (int o = 32; o; o >>= 1) {
                dt1 += __shfl_xor(dt1, o); cn1 += __shfl_xor(cn1, o);
                dt2 += __shfl_xor(dt2, o); cn2 += __shfl_xor(cn2, o);
            }
            double n1 = sqrt(cn1) + EPS_D, n2 = sqrt(cn2) + EPS_D;
            if (lane == 0) {
                if (s < TS)     S[s]     = (float)(fabs(dt1) / (nprev * n1));
                if (s + 1 < TS) S[s + 1] = (float)(fabs(dt2) / (n1 * n2));
            }
            nprev = n2;
#pragma unroll
            for (int j = 0; j < 16; ++j) P[j] = cC[j];
        }
        // single tail (i = 18)
        {
            int s = s0 + 18;
            float cB[16];
            loadrow(vb + (size_t)min(s + 1, TS) * D, lane, cB);
            double dt1, cn1;
            dot_norm(P, cB, dt1, cn1);
#pragma unroll
            for (int o = 32; o; o >>= 1) {
                dt1 += __shfl_xor(dt1, o); cn1 += __shfl_xor(cn1, o);
            }
            double n1 = sqrt(cn1) + EPS_D;
            if (lane == 0 && s < TS)
                S[s] = (float)(fabs(dt1) / (nprev * n1));
        }
    }

    // ---- k=0 gather (t is always 0) overlapped with Phase B ----
    {
        const float4* vs = (const float4*)vb;
        float4*       vd = (float4*)(out + (size_t)b * KP1 * D);
        if (tid < 256) vd[tid] = vs[tid];
        else if (tid < 256 + DA / 4) {
            int off = tid - 256;
            const float4* as = (const float4*)(audio + (size_t)b * T * DA);
            float4* ad = (float4*)(out + (size_t)B * KP1 * D + (size_t)b * KP1 * DA);
            ad[off] = as[off];
        }
    }
    __syncthreads();

    // ---- Phase B: rank-select ----
    // rank(e) = #{j : S[j]<S[e] || (S[j]==S[e] && j<e)}; ranks unique.
    if (tid < TS) {
        float val = S[tid];
        int rank = 0;
#pragma unroll 4
        for (int j = 0; j < TS; ++j) {
            float sj = S[j];
            rank += (sj < val) || (sj == val && j < tid);
        }
        if (rank < K) idxs[rank + 1] = tid + 1;
    }
    __syncthreads();

    // ---- Phase C: gather rows k=1..32 ----
    int grp  = tid >> 8;     // 0..3: four 256-thread groups, 4 rows in flight
    int l256 = tid & 255;
    for (int k = 1 + grp; k < KP1; k += 4) {
        int t = idxs[k];
        const float4* vs = (const float4*)(vb + (size_t)t * D);
        float4*       vd = (float4*)(out + ((size_t)b * KP1 + k) * D);
        vd[l256] = vs[l256];
    }
    const float* ab   = audio + (size_t)b * T * DA;
    float*       outA = out + (size_t)B * KP1 * D + (size_t)b * KP1 * DA;
    for (int a = tid; a < K * (DA / 4); a += 1024) {
        int k = 1 + (a >> 5), off = a & 31;
        int t = idxs[k];
        ((float4*)(outA + (size_t)k * DA))[off] =
            ((const float4*)(ab + (size_t)t * DA))[off];
    }
}

extern "C" void kernel_launch(void* const* d_in, const int* in_sizes, int n_in,
                              void* d_out, int out_size, void* d_ws, size_t ws_size,
                              hipStream_t stream) {
    const float* video = (const float*)d_in[0];
    const float* audio = (const float*)d_in[1];
    float* out = (float*)d_out;

    fused3_kernel<<<B, 1024, 0, stream>>>(video, audio, out);
}

// Round 16
// 49.717 us; speedup vs baseline: 1.0416x; 1.0416x over previous
//
#include <hip/hip_runtime.h>
#include <math.h>

// Problem constants (fixed by reference setup_inputs)
constexpr int B   = 128;
constexpr int T   = 300;
constexpr int D   = 1024;   // video dim
constexpr int DA  = 128;    // audio dim
constexpr int TS  = T - 1;  // 299 similarities per batch
constexpr int K   = 32;
constexpr int KP1 = K + 1;

constexpr int SEGW = 19;    // sims per wave: 16 waves * 19 = 304 >= 299

#define EPS_D 1e-5

__device__ __forceinline__ void loadrow(const float* __restrict__ row, int lane, float r[16]) {
    const float4* f = (const float4*)row;
#pragma unroll
    for (int j = 0; j < 4; ++j) {
        float4 x = f[lane + 64 * j];
        r[4 * j + 0] = x.x; r[4 * j + 1] = x.y;
        r[4 * j + 2] = x.z; r[4 * j + 3] = x.w;
    }
}

// dt = <p,c>, cn = <c,c>, each as two 8-deep f64 chains (same order as R12 —
// bit-identical numerics; f64 is REQUIRED: top-32 sims cluster near 0 with
// order-stat gaps ~1.3e-4 and f32 accumulation error ~1e-6 would flip ranks
// vs the reference ordering).
__device__ __forceinline__ void dot_norm(const float p[16], const float c[16],
                                         double& dt, double& cn) {
    double d0 = 0.0, d1 = 0.0, n0 = 0.0, n1 = 0.0;
#pragma unroll
    for (int j = 0; j < 8; ++j) {
        d0 += (double)p[j] * (double)c[j];
        n0 += (double)c[j] * (double)c[j];
    }
#pragma unroll
    for (int j = 8; j < 16; ++j) {
        d1 += (double)p[j] * (double)c[j];
        n1 += (double)c[j] * (double)c[j];
    }
    dt = d0 + d1; cn = n0 + n1;
}

// One block per batch, 1024 threads, ONE dispatch total.
// R12's exact pair-ILP body (best measured: 49.7 us) + __launch_bounds__
// (1024, 4): 16-wave block at 4 waves/EU == 1 block/CU -> 128-VGPR budget,
// eliminating the mild spill R12 ran with at the default 64-VGPR cap
// (R13/R14 verified this bound removes spill writes).
// Phase A: 16 waves x 19 sims, paired iterations (2 rows, 2 sims, 4 f64
//   butterflies batched). absmax 0.0 in 9 prior runs.
// Phase B: LDS rank-select (rank<K == top_k(-sim) stable winners).
// Phase C: gather 33 video+audio rows (L2/L3-warm from phase A).
__global__ __launch_bounds__(1024, 4) void fused2_kernel(const float* __restrict__ video,
                                                         const float* __restrict__ audio,
                                                         float* __restrict__ out) {
    __shared__ float S[TS];
    __shared__ int   idxs[KP1];

    int b    = blockIdx.x;
    int tid  = threadIdx.x;
    int w    = tid >> 6;
    int lane = tid & 63;

    const float* vb = video + (size_t)b * T * D;

    // ---- Phase A ----
    {
        int s0 = w * SEGW;
        float P[16];
        loadrow(vb + (size_t)min(s0, TS) * D, lane, P);

        double pn0 = 0.0, pn1 = 0.0;
#pragma unroll
        for (int j = 0; j < 8; ++j)  pn0 += (double)P[j] * (double)P[j];
#pragma unroll
        for (int j = 8; j < 16; ++j) pn1 += (double)P[j] * (double)P[j];
        double pn = pn0 + pn1;
#pragma unroll
        for (int o = 32; o; o >>= 1) pn += __shfl_xor(pn, o);
        double nprev = sqrt(pn) + EPS_D;

        // 9 paired iterations (18 sims) ...
#pragma unroll
        for (int i = 0; i < SEGW - 1; i += 2) {
            int s = s0 + i;
            float cB[16], cC[16];
            loadrow(vb + (size_t)min(s + 1, TS) * D, lane, cB);
            loadrow(vb + (size_t)min(s + 2, TS) * D, lane, cC);

            double dtB, cnB, dtC, cnC;
            dot_norm(P,  cB, dtB, cnB);
            dot_norm(cB, cC, dtC, cnC);
#pragma unroll
            for (int o = 32; o; o >>= 1) {
                dtB += __shfl_xor(dtB, o); cnB += __shfl_xor(cnB, o);
                dtC += __shfl_xor(dtC, o); cnC += __shfl_xor(cnC, o);
            }
            double nB = sqrt(cnB) + EPS_D;
            double nC = sqrt(cnC) + EPS_D;
            if (lane == 0) {
                if (s < TS)     S[s]     = (float)(fabs(dtB) / (nprev * nB));
                if (s + 1 < TS) S[s + 1] = (float)(fabs(dtC) / (nB * nC));
            }
            nprev = nC;
#pragma unroll
            for (int j = 0; j < 16; ++j) P[j] = cC[j];
        }
        // ... plus the odd tail sim (i = 18)
        {
            int s = s0 + (SEGW - 1);
            float cB[16];
            loadrow(vb + (size_t)min(s + 1, TS) * D, lane, cB);
            double dtB, cnB;
            dot_norm(P, cB, dtB, cnB);
#pragma unroll
            for (int o = 32; o; o >>= 1) {
                dtB += __shfl_xor(dtB, o); cnB += __shfl_xor(cnB, o);
            }
            double nB = sqrt(cnB) + EPS_D;
            if (lane == 0 && s < TS)
                S[s] = (float)(fabs(dtB) / (nprev * nB));
        }
    }
    __syncthreads();

    // ---- Phase B: rank-select ----
    // rank(e) = #{j : S[j]<S[e] || (S[j]==S[e] && j<e)}; ranks unique.
    if (tid == 0) idxs[0] = 0;
    if (tid < TS) {
        float val = S[tid];
        int rank = 0;
#pragma unroll 4
        for (int j = 0; j < TS; ++j) {
            float sj = S[j];
            rank += (sj < val) || (sj == val && j < tid);
        }
        if (rank < K) idxs[rank + 1] = tid + 1;
    }
    __syncthreads();

    // ---- Phase C: gather ----
    int grp  = tid >> 8;     // 0..3: four 256-thread groups, 4 rows in flight
    int l256 = tid & 255;
    for (int k = grp; k < KP1; k += 4) {
        int t = idxs[k];
        const float4* vs = (const float4*)(vb + (size_t)t * D);
        float4*       vd = (float4*)(out + ((size_t)b * KP1 + k) * D);
        vd[l256] = vs[l256];
    }
    const float* ab   = audio + (size_t)b * T * DA;
    float*       outA = out + (size_t)B * KP1 * D + (size_t)b * KP1 * DA;
    for (int a = tid; a < KP1 * (DA / 4); a += 1024) {
        int k = a >> 5, off = a & 31;
        int t = idxs[k];
        ((float4*)(outA + (size_t)k * DA))[off] =
            ((const float4*)(ab + (size_t)t * DA))[off];
    }
}

extern "C" void kernel_launch(void* const* d_in, const int* in_sizes, int n_in,
                              void* d_out, int out_size, void* d_ws, size_t ws_size,
                              hipStream_t stream) {
    const float* video = (const float*)d_in[0];
    const float* audio = (const float*)d_in[1];
    float* out = (float*)d_out;

    fused2_kernel<<<B, 1024, 0, stream>>>(video, audio, out);
}